// Round 2
// baseline (686.852 us; speedup 1.0000x reference)
//
#include <hip/hip_runtime.h>

typedef unsigned short u16;
typedef unsigned int u32;
typedef __bf16 bf16x8 __attribute__((ext_vector_type(8)));
typedef float f32x4 __attribute__((ext_vector_type(4)));

#define SEQ 2048
#define NH 16
#define PD 64
#define DM 1024

__device__ __forceinline__ float bf2f(u16 s) {
  u32 t = ((u32)s) << 16;
  float f;
  __builtin_memcpy(&f, &t, 4);
  return f;
}
__device__ __forceinline__ u16 f2bf(float f) {
  u32 x;
  __builtin_memcpy(&x, &f, 4);
  x = (x + 0x7fffu + ((x >> 16) & 1u)) >> 16;
  return (u16)x;
}

// ---------------- dtype detection ----------------
// Probe Wq (nonzero gaussians). fp32 buffer: lo-halves of floats are either
// ~uniform random (huge bf16 exponents ~45%) or exactly 0 (bf16-rounded values
// stored as fp32). True bf16 buffer: neither. flag=1 -> inputs are fp32.
__global__ __launch_bounds__(256) void detect_kernel(const u16* __restrict__ probe,
                                                     int* __restrict__ flag) {
  __shared__ int sz[256], sh[256];
  int tid = threadIdx.x;
  int zeros = 0, huge = 0;
  for (int j = 0; j < 16; ++j) {
    int i = tid * 16 + j;
    u16 v = probe[i];
    int e = (v >> 7) & 0xFF;
    if (((i & 1) == 0) && v == 0) zeros++;
    if (e >= 0x8C) huge++;  // |x| >= 2^13 or NaN/inf as bf16
  }
  sz[tid] = zeros; sh[tid] = huge;
  __syncthreads();
  for (int s = 128; s > 0; s >>= 1) {
    if (tid < s) { sz[tid] += sz[tid + s]; sh[tid] += sh[tid + s]; }
    __syncthreads();
  }
  if (tid == 0) *flag = (sz[0] > 1024 || sh[0] > 200) ? 1 : 0;
}

// ---------------- convert x (4M elems) to bf16 ----------------
__global__ __launch_bounds__(256) void convert_x_kernel(const void* __restrict__ src,
                                                        u16* __restrict__ dst,
                                                        const int* __restrict__ flag) {
  int i = (blockIdx.x * 256 + threadIdx.x) * 4;
  if (*flag) {
    float4 f = *(const float4*)((const float*)src + i);
    u16 o[4] = {f2bf(f.x), f2bf(f.y), f2bf(f.z), f2bf(f.w)};
    *(uint2*)(dst + i) = *(const uint2*)o;
  } else {
    *(uint2*)(dst + i) = *(const uint2*)((const u16*)src + i);
  }
}

// ---------------- convert biases + u + v to fp32 params ----------------
// layout: [bq, bk, bv, bp, bo, u, v] x 1024 floats
struct ParamPtrs { const void* p[7]; };
__global__ __launch_bounds__(256) void convert_params_kernel(ParamPtrs pp,
                                                             float* __restrict__ pf,
                                                             const int* __restrict__ flag) {
  int idx = blockIdx.x * 256 + threadIdx.x;  // 7168 total
  int seg = idx >> 10, off = idx & 1023;
  const void* s = pp.p[seg];
  pf[idx] = (*flag) ? ((const float*)s)[off] : bf2f(((const u16*)s)[off]);
}

// ---------------- sinusoid position embedding [SEQ, DM] (bf16) ----------------
__global__ __launch_bounds__(256) void sinusoid_kernel(u16* __restrict__ out) {
  int idx = blockIdx.x * 256 + threadIdx.x;
  int s = idx >> 10;
  int i = idx & 1023;
  int j = i & 511;
  float invf = __expf(-(float)j * (9.210340371976184f / 512.0f));
  float ang = (float)s * invf;
  float val = (i < 512) ? sinf(ang) : cosf(ang);
  out[idx] = f2bf(val);
}

// ---------------- transpose + convert the five 1024x1024 weights (W -> W^T bf16) ----------------
__global__ __launch_bounds__(256) void transpose5_kernel(
    const void* __restrict__ w0, const void* __restrict__ w1,
    const void* __restrict__ w2, const void* __restrict__ w3,
    const void* __restrict__ w4, u16* __restrict__ dst,
    const int* __restrict__ flag) {
  __shared__ u16 t[64][72];
  int z = blockIdx.z;
  const void* src = (z == 0) ? w0 : (z == 1) ? w1 : (z == 2) ? w2 : (z == 3) ? w3 : w4;
  u16* out = dst + (size_t)z * DM * DM;
  int r0 = blockIdx.y * 64, c0 = blockIdx.x * 64;
  int tr = threadIdx.x >> 2;
  int tc = (threadIdx.x & 3) * 16;
  if (*flag) {
    const float* g = (const float*)src + (size_t)(r0 + tr) * DM + c0 + tc;
#pragma unroll
    for (int q = 0; q < 4; ++q) {
      float4 f = *(const float4*)(g + q * 4);
      t[tr][tc + q * 4 + 0] = f2bf(f.x);
      t[tr][tc + q * 4 + 1] = f2bf(f.y);
      t[tr][tc + q * 4 + 2] = f2bf(f.z);
      t[tr][tc + q * 4 + 3] = f2bf(f.w);
    }
  } else {
    const uint4* g = (const uint4*)((const u16*)src + (size_t)(r0 + tr) * DM + c0 + tc);
    uint4 a = g[0], bb = g[1];
    *(uint4*)&t[tr][tc] = a;
    *(uint4*)&t[tr][tc + 8] = bb;
  }
  __syncthreads();
  u16 tmp[16] __attribute__((aligned(16)));
#pragma unroll
  for (int jj = 0; jj < 16; ++jj) tmp[jj] = t[tc + jj][tr];
  uint4* o = (uint4*)(out + (size_t)(c0 + tr) * DM + r0 + tc);
  o[0] = *(const uint4*)&tmp[0];
  o[1] = *(const uint4*)&tmp[8];
}

// ---------------- transpose V [B,S,H,P] -> Vt [B,H,P,S] (bf16 ws -> bf16 ws) ----------------
__global__ __launch_bounds__(256) void transpose_v_kernel(
    const u16* __restrict__ V, u16* __restrict__ Vt) {
  __shared__ u16 t[64][72];
  int s0 = blockIdx.x * 64;
  int bh = blockIdx.y;
  int b = bh >> 4, h = bh & 15;
  int tr = threadIdx.x >> 2;
  int tc = (threadIdx.x & 3) * 16;
  const uint4* g = (const uint4*)(V + ((size_t)(b * SEQ + s0 + tr) * NH + h) * PD + tc);
  uint4 a = g[0], bb = g[1];
  *(uint4*)&t[tr][tc] = a;
  *(uint4*)&t[tr][tc + 8] = bb;
  __syncthreads();
  u16 tmp[16] __attribute__((aligned(16)));
#pragma unroll
  for (int jj = 0; jj < 16; ++jj) tmp[jj] = t[tc + jj][tr];
  uint4* o = (uint4*)(Vt + ((size_t)(b * NH + h) * PD + tr) * SEQ + s0 + tc);
  o[0] = *(const uint4*)&tmp[0];
  o[1] = *(const uint4*)&tmp[8];
}

// ---------------- bf16 GEMM: C[M,N] = A[M,K] @ Bt[N,K]^T + bias, 128x128x32 tiles ----------------
struct GemmArgs {
  const u16* A;
  const u16* Bt0; const u16* Bt1; const u16* Bt2;
  const float* b0; const float* b1; const float* b2;
  void* C0; void* C1; void* C2;
  int N, K;
  const int* flag; int outFp32;  // outFp32: store fp32 iff (*flag)
};

__global__ __launch_bounds__(256) void gemm_bt_kernel(GemmArgs p) {
  __shared__ u16 As[128 * 32];
  __shared__ u16 Bs[128 * 32];
  int z = blockIdx.z;
  const u16* A = p.A;
  const u16* Bt = (z == 0) ? p.Bt0 : (z == 1) ? p.Bt1 : p.Bt2;
  const float* bias = (z == 0) ? p.b0 : (z == 1) ? p.b1 : p.b2;
  void* Cv = (z == 0) ? p.C0 : (z == 1) ? p.C1 : p.C2;
  int K = p.K, N = p.N;
  bool f32o = p.outFp32 && (*p.flag);

  int tid = threadIdx.x;
  int wave = tid >> 6, lane = tid & 63;
  int quad = lane >> 4, l16 = lane & 15;
  int m0 = blockIdx.y * 128, n0 = blockIdx.x * 128;
  int wm = (wave >> 1) * 64, wn = (wave & 1) * 64;
  int srow = tid >> 1, scol = (tid & 1) * 16;

  f32x4 acc[4][4] = {};

  const u16* ga = A + (size_t)(m0 + srow) * K + scol;
  const u16* gb = Bt + (size_t)(n0 + srow) * K + scol;

  for (int k0 = 0; k0 < K; k0 += 32) {
    uint4 a0 = *(const uint4*)(ga + k0);
    uint4 a1 = *(const uint4*)(ga + k0 + 8);
    uint4 b0 = *(const uint4*)(gb + k0);
    uint4 b1 = *(const uint4*)(gb + k0 + 8);
    __syncthreads();
    *(uint4*)&As[srow * 32 + scol] = a0;
    *(uint4*)&As[srow * 32 + scol + 8] = a1;
    *(uint4*)&Bs[srow * 32 + scol] = b0;
    *(uint4*)&Bs[srow * 32 + scol + 8] = b1;
    __syncthreads();
    bf16x8 af[4], bfv[4];
#pragma unroll
    for (int i = 0; i < 4; ++i) {
      af[i] = *(const bf16x8*)&As[(wm + i * 16 + l16) * 32 + quad * 8];
      bfv[i] = *(const bf16x8*)&Bs[(wn + i * 16 + l16) * 32 + quad * 8];
    }
#pragma unroll
    for (int tm = 0; tm < 4; ++tm)
#pragma unroll
      for (int tn = 0; tn < 4; ++tn)
        acc[tm][tn] = __builtin_amdgcn_mfma_f32_16x16x32_bf16(af[tm], bfv[tn], acc[tm][tn], 0, 0, 0);
  }

#pragma unroll
  for (int tm = 0; tm < 4; ++tm) {
    int row = m0 + wm + tm * 16 + quad * 4;
#pragma unroll
    for (int tn = 0; tn < 4; ++tn) {
      int col = n0 + wn + tn * 16 + l16;
      float bv = bias[col];
#pragma unroll
      for (int r = 0; r < 4; ++r) {
        float val = acc[tm][tn][r] + bv;
        if (f32o) ((float*)Cv)[(size_t)(row + r) * N + col] = val;
        else ((u16*)Cv)[(size_t)(row + r) * N + col] = f2bf(val);
      }
    }
  }
}

// ---------------- fused rel-attention ----------------
// Grid: (S/64 q-blocks, B*H). 256 threads = 4 waves, wave w owns q-rows [w*16, w*16+16).
// Relative shift handled as a bijective scatter of Ppos[s][t] = (q_s+v)·r_t:
//   z = s+t+1; z >= S -> Sc[s-s0][z-S-j0] ; z < S -> Sc[s-s0-1][z-j0]; OOB targets skipped.
__global__ __launch_bounds__(256) void attn_kernel(
    const u16* __restrict__ Q, const u16* __restrict__ Kg,
    const u16* __restrict__ Vtg, const u16* __restrict__ Rg,
    const float* __restrict__ pf,
    u16* __restrict__ O) {
  __shared__ u16 Qu[64][64];       // q + u
  __shared__ u16 Qv[65][64];       // q + v (extra row s0+64 for the shift tail)
  __shared__ u16 Ks[64][64];       // K tile [t][p]
  __shared__ u16 Vs[64][64];       // V^T tile [p][t]
  __shared__ u16 RsPb[64 * 64];    // overlay: R band tile [t][p]  /  P probs [s][t] (bf16)
  __shared__ float Sc[64][68];     // fp32 scores (content + scattered pos)

  int tid = threadIdx.x, wave = tid >> 6, lane = tid & 63;
  int quad = lane >> 4, l16 = lane & 15;
  int s0 = blockIdx.x * 64;
  int bh = blockIdx.y, b = bh >> 4, h = bh & 15;
  const float* pu = pf + 5 * 1024 + h * PD;
  const float* pv = pf + 6 * 1024 + h * PD;

  // load Qu/Qv
  {
    int si = tid >> 2, pc = (tid & 3) * 16;
    const u16* qrow = Q + ((size_t)(b * SEQ + s0 + si)) * DM + h * PD + pc;
#pragma unroll
    for (int j = 0; j < 16; ++j) {
      float qf = bf2f(qrow[j]);
      Qu[si][pc + j] = f2bf(qf + pu[pc + j]);
      Qv[si][pc + j] = f2bf(qf + pv[pc + j]);
    }
    if (tid < 4) {
      int pc2 = tid * 16;
#pragma unroll
      for (int j = 0; j < 16; ++j) {
        float val = 0.f;
        if (s0 + 64 < SEQ)
          val = bf2f(Q[((size_t)(b * SEQ + s0 + 64)) * DM + h * PD + pc2 + j]) + pv[pc2 + j];
        Qv[64][pc2 + j] = f2bf(val);
      }
    }
  }

  float m_i = -1e30f, l_i = 0.f;
  f32x4 oacc[4] = {};
  int rw = lane >> 2, cg = lane & 3;
  int myrow = wave * 16 + rw;

  for (int j0 = 0; j0 < SEQ; j0 += 64) {
    __syncthreads();  // prev PV reads of Vs/Pb done before restaging
    {
      int tl = tid >> 2, pc = (tid & 3) * 16;
      const uint4* ksrc = (const uint4*)(Kg + ((size_t)(b * SEQ + j0 + tl)) * DM + h * PD + pc);
      uint4 kv0 = ksrc[0], kv1 = ksrc[1];
      const uint4* vsrc = (const uint4*)(Vtg + ((size_t)(b * NH + h) * PD + tl) * SEQ + j0 + pc);
      uint4 vv0 = vsrc[0], vv1 = vsrc[1];
      *(uint4*)&Ks[tl][pc] = kv0;
      *(uint4*)&Ks[tl][pc + 8] = kv1;
      *(uint4*)&Vs[tl][pc] = vv0;
      *(uint4*)&Vs[tl][pc + 8] = vv1;
    }
    __syncthreads();
    // content scores: Sc[s][t] = (q+u)·k
#pragma unroll
    for (int tn = 0; tn < 4; ++tn) {
      f32x4 acc = {};
#pragma unroll
      for (int kk = 0; kk < 2; ++kk) {
        bf16x8 a = *(const bf16x8*)&Qu[wave * 16 + l16][kk * 32 + quad * 8];
        bf16x8 bb = *(const bf16x8*)&Ks[tn * 16 + l16][kk * 32 + quad * 8];
        acc = __builtin_amdgcn_mfma_f32_16x16x32_bf16(a, bb, acc, 0, 0, 0);
      }
#pragma unroll
      for (int r = 0; r < 4; ++r)
        Sc[wave * 16 + quad * 4 + r][tn * 16 + l16] = acc[r];
    }
    __syncthreads();

    // positional passes: pass 0 = main band, pass 1 = tail band; two 64-wide halves each
#pragma unroll 1
    for (int sp = 0; sp < 4; ++sp) {
      int pass = sp >> 1;
      int half = sp & 1;
      int tb0 = ((pass == 0) ? (SEQ - 65 + j0 - s0) : (j0 - s0 - 65)) + half * 64;
      if (tb0 >= SEQ || tb0 + 64 <= 0) continue;  // block-uniform
      {
        int rn = tid >> 2, pc = (tid & 3) * 16;
        int tg = tb0 + rn;
        uint4* dstp = (uint4*)&RsPb[rn * 64 + pc];
        if (tg >= 0 && tg < SEQ) {
          const uint4* rsrc = (const uint4*)(Rg + (size_t)tg * DM + h * PD + pc);
          uint4 r0v = rsrc[0], r1v = rsrc[1];
          dstp[0] = r0v;
          dstp[1] = r1v;
        } else {
          uint4 zz = make_uint4(0, 0, 0, 0);
          dstp[0] = zz;
          dstp[1] = zz;
        }
      }
      __syncthreads();
#pragma unroll
      for (int tt = 0; tt < 4; ++tt) {
        f32x4 acc = {};
#pragma unroll
        for (int kk = 0; kk < 2; ++kk) {
          bf16x8 a = *(const bf16x8*)&Qv[pass + wave * 16 + l16][kk * 32 + quad * 8];
          bf16x8 bb = *(const bf16x8*)&RsPb[(tt * 16 + l16) * 64 + kk * 32 + quad * 8];
          acc = __builtin_amdgcn_mfma_f32_16x16x32_bf16(a, bb, acc, 0, 0, 0);
        }
        int tg = tb0 + tt * 16 + l16;
        if (tg >= 0 && tg < SEQ) {
#pragma unroll
          for (int r = 0; r < 4; ++r) {
            int sg = s0 + pass + wave * 16 + quad * 4 + r;
            int zz = sg + tg + 1;
            int row_l, col;
            if (zz >= SEQ) {
              row_l = sg - s0;
              col = zz - SEQ - j0;
            } else {
              row_l = sg - s0 - 1;
              col = zz - j0;
            }
            if (row_l >= 0 && row_l < 64 && col >= 0 && col < 64)
              Sc[row_l][col] += acc[r];  // bijection: no two lanes hit the same cell
          }
        }
      }
      __syncthreads();
    }

    // online softmax: 4 lanes per row, 16 cols per lane
    float vals[16];
#pragma unroll
    for (int j = 0; j < 16; ++j) vals[j] = Sc[myrow][cg * 16 + j] * 0.125f;
    float mx = vals[0];
#pragma unroll
    for (int j = 1; j < 16; ++j) mx = fmaxf(mx, vals[j]);
    mx = fmaxf(mx, __shfl_xor(mx, 1));
    mx = fmaxf(mx, __shfl_xor(mx, 2));
    float m_new = fmaxf(m_i, mx);
    float alpha = __expf(m_i - m_new);
    float ssum = 0.f;
#pragma unroll
    for (int j = 0; j < 16; ++j) {
      float pcur = __expf(vals[j] - m_new);
      u16 pb = f2bf(pcur);
      RsPb[myrow * 64 + cg * 16 + j] = pb;  // Pb overlay
      ssum += bf2f(pb);
    }
    ssum += __shfl_xor(ssum, 1);
    ssum += __shfl_xor(ssum, 2);
    l_i = l_i * alpha + ssum;
    m_i = m_new;
    __syncthreads();

    // PV: O = O*alpha + P @ V
    float ar[4];
#pragma unroll
    for (int r = 0; r < 4; ++r) ar[r] = __shfl(alpha, (quad * 4 + r) * 4);
#pragma unroll
    for (int tp = 0; tp < 4; ++tp) {
#pragma unroll
      for (int r = 0; r < 4; ++r) oacc[tp][r] *= ar[r];
#pragma unroll
      for (int kk = 0; kk < 2; ++kk) {
        bf16x8 a = *(const bf16x8*)&RsPb[(wave * 16 + l16) * 64 + kk * 32 + quad * 8];
        bf16x8 bb = *(const bf16x8*)&Vs[tp * 16 + l16][kk * 32 + quad * 8];
        oacc[tp] = __builtin_amdgcn_mfma_f32_16x16x32_bf16(a, bb, oacc[tp], 0, 0, 0);
      }
    }
  }

  float lr[4];
#pragma unroll
  for (int r = 0; r < 4; ++r) lr[r] = 1.f / __shfl(l_i, (quad * 4 + r) * 4);
#pragma unroll
  for (int tp = 0; tp < 4; ++tp) {
    int p = tp * 16 + l16;
#pragma unroll
    for (int r = 0; r < 4; ++r) {
      int srow_g = s0 + wave * 16 + quad * 4 + r;
      O[((size_t)(b * SEQ + srow_g)) * DM + h * PD + p] = f2bf(oacc[tp][r] * lr[r]);
    }
  }
}

extern "C" void kernel_launch(void* const* d_in, const int* in_sizes, int n_in,
                              void* d_out, int out_size, void* d_ws, size_t ws_size,
                              hipStream_t stream) {
  (void)in_sizes; (void)n_in; (void)out_size; (void)ws_size;
  const void* x  = d_in[0];
  const void* Wq = d_in[1];
  const void* bq = d_in[2];
  const void* Wk = d_in[3];
  const void* bk = d_in[4];
  const void* Wv = d_in[5];
  const void* bv = d_in[6];
  const void* Wp = d_in[7];
  const void* bp = d_in[8];
  const void* Wo = d_in[9];
  const void* bo = d_in[10];
  const void* u  = d_in[11];
  const void* v  = d_in[12];

  char* base = (char*)d_ws;
  int* flag = (int*)base;
  float* pf = (float*)(base + 64);                       // 7168 floats
  u16* wbase = (u16*)(base + 64 + 7168 * 4);             // 32B-aligned
  u16* WT   = wbase;                                     // 5M
  u16* xb   = WT + (size_t)5 * DM * DM;                  // 4M (aliased: Vtb)
  u16* sinb = xb + (size_t)2 * SEQ * DM;                 // 2M
  u16* Qb   = sinb + (size_t)SEQ * DM;                   // 4M
  u16* Kb   = Qb + (size_t)2 * SEQ * DM;                 // 4M
  u16* Vb   = Kb + (size_t)2 * SEQ * DM;                 // 4M (aliased: attn out)
  u16* Rb   = Vb + (size_t)2 * SEQ * DM;                 // 2M
  u16* Vtb  = xb;   // x consumed by QKV gemm before transpose_v writes here
  u16* Ab   = Vb;   // V consumed by transpose_v before attention writes here

  detect_kernel<<<1, 256, 0, stream>>>((const u16*)Wq, flag);

  convert_x_kernel<<<(2 * SEQ * DM) / 1024, 256, 0, stream>>>(x, xb, flag);
  ParamPtrs pp;
  pp.p[0] = bq; pp.p[1] = bk; pp.p[2] = bv; pp.p[3] = bp; pp.p[4] = bo;
  pp.p[5] = u;  pp.p[6] = v;
  convert_params_kernel<<<28, 256, 0, stream>>>(pp, pf, flag);

  sinusoid_kernel<<<(SEQ * DM) / 256, 256, 0, stream>>>(sinb);
  transpose5_kernel<<<dim3(16, 16, 5), 256, 0, stream>>>(Wq, Wk, Wv, Wp, Wo, WT, flag);

  GemmArgs qkv;
  qkv.A = xb;
  qkv.Bt0 = WT; qkv.Bt1 = WT + (size_t)DM * DM; qkv.Bt2 = WT + (size_t)2 * DM * DM;
  qkv.b0 = pf; qkv.b1 = pf + 1024; qkv.b2 = pf + 2048;
  qkv.C0 = Qb; qkv.C1 = Kb; qkv.C2 = Vb;
  qkv.N = DM; qkv.K = DM; qkv.flag = flag; qkv.outFp32 = 0;
  gemm_bt_kernel<<<dim3(8, 32, 3), 256, 0, stream>>>(qkv);

  GemmArgs pr;
  pr.A = sinb;
  pr.Bt0 = WT + (size_t)3 * DM * DM; pr.Bt1 = pr.Bt0; pr.Bt2 = pr.Bt0;
  pr.b0 = pf + 3072; pr.b1 = pr.b0; pr.b2 = pr.b0;
  pr.C0 = Rb; pr.C1 = Rb; pr.C2 = Rb;
  pr.N = DM; pr.K = DM; pr.flag = flag; pr.outFp32 = 0;
  gemm_bt_kernel<<<dim3(8, 16, 1), 256, 0, stream>>>(pr);

  transpose_v_kernel<<<dim3(32, 32), 256, 0, stream>>>(Vb, Vtb);
  attn_kernel<<<dim3(32, 32), 256, 0, stream>>>(Qb, Kb, Vtb, Rb, pf, Ab);

  GemmArgs fo;
  fo.A = Ab;
  fo.Bt0 = WT + (size_t)4 * DM * DM; fo.Bt1 = fo.Bt0; fo.Bt2 = fo.Bt0;
  fo.b0 = pf + 4096; fo.b1 = fo.b0; fo.b2 = fo.b0;
  fo.C0 = d_out; fo.C1 = d_out; fo.C2 = d_out;
  fo.N = DM; fo.K = DM; fo.flag = flag; fo.outFp32 = 1;
  gemm_bt_kernel<<<dim3(8, 32, 1), 256, 0, stream>>>(fo);
}

// Round 3
// 561.657 us; speedup vs baseline: 1.2229x; 1.2229x over previous
//
#include <hip/hip_runtime.h>

typedef unsigned short u16;
typedef unsigned int u32;
typedef __bf16 bf16x8 __attribute__((ext_vector_type(8)));
typedef float f32x4 __attribute__((ext_vector_type(4)));

#define SEQ 2048
#define NH 16
#define PD 64
#define DM 1024

__device__ __forceinline__ float bf2f(u16 s) {
  u32 t = ((u32)s) << 16;
  float f;
  __builtin_memcpy(&f, &t, 4);
  return f;
}
__device__ __forceinline__ u16 f2bf(float f) {
  u32 x;
  __builtin_memcpy(&x, &f, 4);
  x = (x + 0x7fffu + ((x >> 16) & 1u)) >> 16;
  return (u16)x;
}

// ---------------- dtype detection (fp32 vs bf16 input buffers) ----------------
__global__ __launch_bounds__(256) void detect_kernel(const u16* __restrict__ probe,
                                                     int* __restrict__ flag) {
  __shared__ int sz[256], sh[256];
  int tid = threadIdx.x;
  int zeros = 0, huge = 0;
  for (int j = 0; j < 16; ++j) {
    int i = tid * 16 + j;
    u16 v = probe[i];
    int e = (v >> 7) & 0xFF;
    if (((i & 1) == 0) && v == 0) zeros++;
    if (e >= 0x8C) huge++;
  }
  sz[tid] = zeros; sh[tid] = huge;
  __syncthreads();
  for (int s = 128; s > 0; s >>= 1) {
    if (tid < s) { sz[tid] += sz[tid + s]; sh[tid] += sh[tid + s]; }
    __syncthreads();
  }
  if (tid == 0) *flag = (sz[0] > 1024 || sh[0] > 200) ? 1 : 0;
}

// ---------------- convert x (4M elems) to bf16 ----------------
__global__ __launch_bounds__(256) void convert_x_kernel(const void* __restrict__ src,
                                                        u16* __restrict__ dst,
                                                        const int* __restrict__ flag) {
  int i = (blockIdx.x * 256 + threadIdx.x) * 4;
  if (*flag) {
    float4 f = *(const float4*)((const float*)src + i);
    u16 o[4] = {f2bf(f.x), f2bf(f.y), f2bf(f.z), f2bf(f.w)};
    *(uint2*)(dst + i) = *(const uint2*)o;
  } else {
    *(uint2*)(dst + i) = *(const uint2*)((const u16*)src + i);
  }
}

// ---------------- convert biases + u + v to fp32 params ----------------
struct ParamPtrs { const void* p[7]; };
__global__ __launch_bounds__(256) void convert_params_kernel(ParamPtrs pp,
                                                             float* __restrict__ pf,
                                                             const int* __restrict__ flag) {
  int idx = blockIdx.x * 256 + threadIdx.x;  // 7168 total
  int seg = idx >> 10, off = idx & 1023;
  const void* s = pp.p[seg];
  pf[idx] = (*flag) ? ((const float*)s)[off] : bf2f(((const u16*)s)[off]);
}

// ---------------- sinusoid position embedding [SEQ, DM] (bf16) ----------------
__global__ __launch_bounds__(256) void sinusoid_kernel(u16* __restrict__ out) {
  int idx = blockIdx.x * 256 + threadIdx.x;
  int s = idx >> 10;
  int i = idx & 1023;
  int j = i & 511;
  float invf = __expf(-(float)j * (9.210340371976184f / 512.0f));
  float ang = (float)s * invf;
  float val = (i < 512) ? sinf(ang) : cosf(ang);
  out[idx] = f2bf(val);
}

// ---------------- transpose + convert the five 1024x1024 weights ----------------
__global__ __launch_bounds__(256) void transpose5_kernel(
    const void* __restrict__ w0, const void* __restrict__ w1,
    const void* __restrict__ w2, const void* __restrict__ w3,
    const void* __restrict__ w4, u16* __restrict__ dst,
    const int* __restrict__ flag) {
  __shared__ u16 t[64][72];
  int z = blockIdx.z;
  const void* src = (z == 0) ? w0 : (z == 1) ? w1 : (z == 2) ? w2 : (z == 3) ? w3 : w4;
  u16* out = dst + (size_t)z * DM * DM;
  int r0 = blockIdx.y * 64, c0 = blockIdx.x * 64;
  int tr = threadIdx.x >> 2;
  int tc = (threadIdx.x & 3) * 16;
  if (*flag) {
    const float* g = (const float*)src + (size_t)(r0 + tr) * DM + c0 + tc;
#pragma unroll
    for (int q = 0; q < 4; ++q) {
      float4 f = *(const float4*)(g + q * 4);
      t[tr][tc + q * 4 + 0] = f2bf(f.x);
      t[tr][tc + q * 4 + 1] = f2bf(f.y);
      t[tr][tc + q * 4 + 2] = f2bf(f.z);
      t[tr][tc + q * 4 + 3] = f2bf(f.w);
    }
  } else {
    const uint4* g = (const uint4*)((const u16*)src + (size_t)(r0 + tr) * DM + c0 + tc);
    uint4 a = g[0], bb = g[1];
    *(uint4*)&t[tr][tc] = a;
    *(uint4*)&t[tr][tc + 8] = bb;
  }
  __syncthreads();
  u16 tmp[16] __attribute__((aligned(16)));
#pragma unroll
  for (int jj = 0; jj < 16; ++jj) tmp[jj] = t[tc + jj][tr];
  uint4* o = (uint4*)(out + (size_t)(c0 + tr) * DM + r0 + tc);
  o[0] = *(const uint4*)&tmp[0];
  o[1] = *(const uint4*)&tmp[8];
}

// ---------------- transpose V [B,S,H,P] -> Vt [B,H,P,S] ----------------
__global__ __launch_bounds__(256) void transpose_v_kernel(
    const u16* __restrict__ V, u16* __restrict__ Vt) {
  __shared__ u16 t[64][72];
  int s0 = blockIdx.x * 64;
  int bh = blockIdx.y;
  int b = bh >> 4, h = bh & 15;
  int tr = threadIdx.x >> 2;
  int tc = (threadIdx.x & 3) * 16;
  const uint4* g = (const uint4*)(V + ((size_t)(b * SEQ + s0 + tr) * NH + h) * PD + tc);
  uint4 a = g[0], bb = g[1];
  *(uint4*)&t[tr][tc] = a;
  *(uint4*)&t[tr][tc + 8] = bb;
  __syncthreads();
  u16 tmp[16] __attribute__((aligned(16)));
#pragma unroll
  for (int jj = 0; jj < 16; ++jj) tmp[jj] = t[tc + jj][tr];
  uint4* o = (uint4*)(Vt + ((size_t)(b * NH + h) * PD + tr) * SEQ + s0 + tc);
  o[0] = *(const uint4*)&tmp[0];
  o[1] = *(const uint4*)&tmp[8];
}

// ---------------- bf16 GEMM, 128x128x32 tiles, LDS stride padded to 40 ----------------
struct GemmArgs {
  const u16* A;
  const u16* Bt0; const u16* Bt1; const u16* Bt2;
  const float* b0; const float* b1; const float* b2;
  void* C0; void* C1; void* C2;
  int N, K;
  const int* flag; int outFp32;
};

__global__ __launch_bounds__(256) void gemm_bt_kernel(GemmArgs p) {
  __shared__ u16 As[128 * 40];
  __shared__ u16 Bs[128 * 40];
  int z = blockIdx.z;
  const u16* A = p.A;
  const u16* Bt = (z == 0) ? p.Bt0 : (z == 1) ? p.Bt1 : p.Bt2;
  const float* bias = (z == 0) ? p.b0 : (z == 1) ? p.b1 : p.b2;
  void* Cv = (z == 0) ? p.C0 : (z == 1) ? p.C1 : p.C2;
  int K = p.K, N = p.N;
  bool f32o = p.outFp32 && (*p.flag);

  int tid = threadIdx.x;
  int wave = tid >> 6, lane = tid & 63;
  int quad = lane >> 4, l16 = lane & 15;
  int m0 = blockIdx.y * 128, n0 = blockIdx.x * 128;
  int wm = (wave >> 1) * 64, wn = (wave & 1) * 64;
  int srow = tid >> 1, scol = (tid & 1) * 16;

  f32x4 acc[4][4] = {};

  const u16* ga = A + (size_t)(m0 + srow) * K + scol;
  const u16* gb = Bt + (size_t)(n0 + srow) * K + scol;

  for (int k0 = 0; k0 < K; k0 += 32) {
    uint4 a0 = *(const uint4*)(ga + k0);
    uint4 a1 = *(const uint4*)(ga + k0 + 8);
    uint4 b0 = *(const uint4*)(gb + k0);
    uint4 b1 = *(const uint4*)(gb + k0 + 8);
    __syncthreads();
    *(uint4*)&As[srow * 40 + scol] = a0;
    *(uint4*)&As[srow * 40 + scol + 8] = a1;
    *(uint4*)&Bs[srow * 40 + scol] = b0;
    *(uint4*)&Bs[srow * 40 + scol + 8] = b1;
    __syncthreads();
    bf16x8 af[4], bfv[4];
#pragma unroll
    for (int i = 0; i < 4; ++i) {
      af[i] = *(const bf16x8*)&As[(wm + i * 16 + l16) * 40 + quad * 8];
      bfv[i] = *(const bf16x8*)&Bs[(wn + i * 16 + l16) * 40 + quad * 8];
    }
#pragma unroll
    for (int tm = 0; tm < 4; ++tm)
#pragma unroll
      for (int tn = 0; tn < 4; ++tn)
        acc[tm][tn] = __builtin_amdgcn_mfma_f32_16x16x32_bf16(af[tm], bfv[tn], acc[tm][tn], 0, 0, 0);
  }

#pragma unroll
  for (int tm = 0; tm < 4; ++tm) {
    int row = m0 + wm + tm * 16 + quad * 4;
#pragma unroll
    for (int tn = 0; tn < 4; ++tn) {
      int col = n0 + wn + tn * 16 + l16;
      float bv = bias[col];
#pragma unroll
      for (int r = 0; r < 4; ++r) {
        float val = acc[tm][tn][r] + bv;
        if (f32o) ((float*)Cv)[(size_t)(row + r) * N + col] = val;
        else ((u16*)Cv)[(size_t)(row + r) * N + col] = f2bf(val);
      }
    }
  }
}

// ---------------- fused rel-attention, register softmax + band gather ----------------
// Per (b,h,64 q-rows). Content scores stay in C-layout registers.
// Positional MFMA results stored transposed bf16: BbT[tband][s_local], then
// gather-add applies the rel-shift: pass0 (c<=s): BbT[64-sl+cl][sl];
// pass1 (c>=s+2): BbT[63-sl+cl][sl]; c==s+1 -> 0. OOB R rows zero-staged.
__global__ __launch_bounds__(256) void attn_kernel(
    const u16* __restrict__ Q, const u16* __restrict__ Kg,
    const u16* __restrict__ Vtg, const u16* __restrict__ Rg,
    const float* __restrict__ pf,
    u16* __restrict__ O) {
  __shared__ __align__(16) u16 Qu[64][72];   // q+u
  __shared__ __align__(16) u16 Qv[65][72];   // q+v (+1 tail row)
  __shared__ __align__(16) u16 KsP[64][72];  // K tile [t][p] / P probs [s][t]
  __shared__ __align__(16) u16 RV[64][72];   // R band tile [t][p] / V^T tile [p][t]
  __shared__ __align__(16) u16 BbT[128][68]; // pos band transposed [tband][s_local]

  int tid = threadIdx.x, wave = tid >> 6, lane = tid & 63;
  int quad = lane >> 4, l16 = lane & 15;
  int s0 = blockIdx.x * 64;
  int bh = blockIdx.y, b = bh >> 4, h = bh & 15;
  const float* pu = pf + 5 * 1024 + h * PD;
  const float* pv = pf + 6 * 1024 + h * PD;

  // prologue: Qu = q+u, Qv = q+v
  {
    int si = tid >> 2, pc = (tid & 3) * 16;
    const u16* qrow = Q + ((size_t)(b * SEQ + s0 + si)) * DM + h * PD + pc;
    u16 qs[16] __attribute__((aligned(16)));
    *(uint4*)&qs[0] = *(const uint4*)qrow;
    *(uint4*)&qs[8] = *(const uint4*)(qrow + 8);
    u16 ou[16] __attribute__((aligned(16)));
    u16 ov[16] __attribute__((aligned(16)));
#pragma unroll
    for (int j = 0; j < 16; ++j) {
      float qf = bf2f(qs[j]);
      ou[j] = f2bf(qf + pu[pc + j]);
      ov[j] = f2bf(qf + pv[pc + j]);
    }
    *(uint4*)&Qu[si][pc] = *(const uint4*)&ou[0];
    *(uint4*)&Qu[si][pc + 8] = *(const uint4*)&ou[8];
    *(uint4*)&Qv[si][pc] = *(const uint4*)&ov[0];
    *(uint4*)&Qv[si][pc + 8] = *(const uint4*)&ov[8];
    if (tid < 4) {
      int pc2 = tid * 16;
#pragma unroll
      for (int j = 0; j < 16; ++j) {
        float val = 0.f;
        if (s0 + 64 < SEQ)
          val = bf2f(Q[((size_t)(b * SEQ + s0 + 64)) * DM + h * PD + pc2 + j]) + pv[pc2 + j];
        Qv[64][pc2 + j] = f2bf(val);
      }
    }
  }

  float m_i[4], l_i[4];
#pragma unroll
  for (int r = 0; r < 4; ++r) { m_i[r] = -1e30f; l_i[r] = 0.f; }
  f32x4 oacc[4] = {};

  int arow = wave * 16 + l16;        // A-frag row (content/PV)
  int sl_base = wave * 16 + quad * 4;  // C-layout row base

  for (int j0 = 0; j0 < SEQ; j0 += 64) {
    __syncthreads();  // prev PV reads of KsP(P) / RV(Vs) done
    {
      int tl = tid >> 2, pc = (tid & 3) * 16;
      const uint4* ksrc = (const uint4*)(Kg + ((size_t)(b * SEQ + j0 + tl)) * DM + h * PD + pc);
      uint4 k0 = ksrc[0], k1 = ksrc[1];
      *(uint4*)&KsP[tl][pc] = k0;
      *(uint4*)&KsP[tl][pc + 8] = k1;
    }
    __syncthreads();

    // content scores -> registers (C-layout)
    f32x4 acc[4];
#pragma unroll
    for (int tn = 0; tn < 4; ++tn) acc[tn] = (f32x4){0.f, 0.f, 0.f, 0.f};
    {
      bf16x8 a0 = *(const bf16x8*)&Qu[arow][quad * 8];
      bf16x8 a1 = *(const bf16x8*)&Qu[arow][32 + quad * 8];
#pragma unroll
      for (int tn = 0; tn < 4; ++tn) {
        bf16x8 b0 = *(const bf16x8*)&KsP[tn * 16 + l16][quad * 8];
        bf16x8 b1 = *(const bf16x8*)&KsP[tn * 16 + l16][32 + quad * 8];
        acc[tn] = __builtin_amdgcn_mfma_f32_16x16x32_bf16(a0, b0, acc[tn], 0, 0, 0);
        acc[tn] = __builtin_amdgcn_mfma_f32_16x16x32_bf16(a1, b1, acc[tn], 0, 0, 0);
      }
    }

    // positional passes
    int nslice = 0;
#pragma unroll 1
    for (int p = 0; p < 2; ++p) {
      int bstart = (p == 0) ? (SEQ - 65 + j0 - s0) : (j0 - s0 - 65);
      bool act0 = (bstart < SEQ) && (bstart + 64 > 0);
      bool act1 = (bstart + 64 < SEQ) && (bstart + 128 > 0);
      if (!act0 && !act1) continue;
      bf16x8 a0 = *(const bf16x8*)&Qv[p + arow][quad * 8];
      bf16x8 a1 = *(const bf16x8*)&Qv[p + arow][32 + quad * 8];
#pragma unroll 1
      for (int hf = 0; hf < 2; ++hf) {
        bool act = hf ? act1 : act0;
        if (!act) continue;
        int tb0 = bstart + hf * 64;
        if (nslice > 0) __syncthreads();  // prev RV reads + gather reads done
        {
          int rn = tid >> 2, pc = (tid & 3) * 16;
          int tg = tb0 + rn;
          uint4 r0v = make_uint4(0, 0, 0, 0), r1v = r0v;
          if (tg >= 0 && tg < SEQ) {
            const uint4* rsrc = (const uint4*)(Rg + (size_t)tg * DM + h * PD + pc);
            r0v = rsrc[0];
            r1v = rsrc[1];
          }
          *(uint4*)&RV[rn][pc] = r0v;
          *(uint4*)&RV[rn][pc + 8] = r1v;
        }
        __syncthreads();
#pragma unroll
        for (int tt = 0; tt < 4; ++tt) {
          f32x4 pacc = (f32x4){0.f, 0.f, 0.f, 0.f};
          bf16x8 b0 = *(const bf16x8*)&RV[tt * 16 + l16][quad * 8];
          bf16x8 b1 = *(const bf16x8*)&RV[tt * 16 + l16][32 + quad * 8];
          pacc = __builtin_amdgcn_mfma_f32_16x16x32_bf16(a0, b0, pacc, 0, 0, 0);
          pacc = __builtin_amdgcn_mfma_f32_16x16x32_bf16(a1, b1, pacc, 0, 0, 0);
          u16 pk[4] __attribute__((aligned(8)));
#pragma unroll
          for (int r = 0; r < 4; ++r) pk[r] = f2bf(pacc[r]);
          *(uint2*)&BbT[hf * 64 + tt * 16 + l16][sl_base] = *(const uint2*)pk;
        }
        ++nslice;
      }
      __syncthreads();  // band stores visible
      // gather-add pass-p contributions (rel-shift applied via indexing)
#pragma unroll
      for (int tn = 0; tn < 4; ++tn) {
        int cg = j0 + tn * 16 + l16;
        int cl = tn * 16 + l16;
#pragma unroll
        for (int r = 0; r < 4; ++r) {
          int sl = sl_base + r;
          int sg = s0 + sl;
          int tband = (p == 0) ? (64 - sl + cl) : (63 - sl + cl);
          bool valid = (p == 0) ? (cg <= sg) : (cg >= sg + 2);
          bool hact = (tband < 64) ? act0 : act1;
          float vread = bf2f(BbT[tband][sl]);
          if (valid && hact) acc[tn][r] += vread;
        }
      }
      ++nslice;  // force sync before next pass's first slice overwrites RV/BbT
    }

    // softmax in C-layout registers
    float alpha_r[4];
#pragma unroll
    for (int r = 0; r < 4; ++r) {
      float v0 = acc[0][r] * 0.125f, v1 = acc[1][r] * 0.125f;
      float v2 = acc[2][r] * 0.125f, v3 = acc[3][r] * 0.125f;
      float mx = fmaxf(fmaxf(v0, v1), fmaxf(v2, v3));
      mx = fmaxf(mx, __shfl_xor(mx, 1));
      mx = fmaxf(mx, __shfl_xor(mx, 2));
      mx = fmaxf(mx, __shfl_xor(mx, 4));
      mx = fmaxf(mx, __shfl_xor(mx, 8));
      float m_new = fmaxf(m_i[r], mx);
      float al = __expf(m_i[r] - m_new);
      u16 q0 = f2bf(__expf(v0 - m_new));
      u16 q1 = f2bf(__expf(v1 - m_new));
      u16 q2 = f2bf(__expf(v2 - m_new));
      u16 q3 = f2bf(__expf(v3 - m_new));
      int row = sl_base + r;
      KsP[row][l16] = q0;
      KsP[row][16 + l16] = q1;
      KsP[row][32 + l16] = q2;
      KsP[row][48 + l16] = q3;
      float ssum = bf2f(q0) + bf2f(q1) + bf2f(q2) + bf2f(q3);
      ssum += __shfl_xor(ssum, 1);
      ssum += __shfl_xor(ssum, 2);
      ssum += __shfl_xor(ssum, 4);
      ssum += __shfl_xor(ssum, 8);
      l_i[r] = l_i[r] * al + ssum;
      m_i[r] = m_new;
      alpha_r[r] = al;
    }

    // stage V^T into RV (R reads done by post-slice sync)
    {
      int tl = tid >> 2, pc = (tid & 3) * 16;
      const uint4* vsrc = (const uint4*)(Vtg + ((size_t)(b * NH + h) * PD + tl) * SEQ + j0 + pc);
      uint4 v0 = vsrc[0], v1 = vsrc[1];
      *(uint4*)&RV[tl][pc] = v0;
      *(uint4*)&RV[tl][pc + 8] = v1;
    }
    __syncthreads();  // P + Vs visible

    // PV
    {
      bf16x8 pa0 = *(const bf16x8*)&KsP[arow][quad * 8];
      bf16x8 pa1 = *(const bf16x8*)&KsP[arow][32 + quad * 8];
#pragma unroll
      for (int tp = 0; tp < 4; ++tp) {
#pragma unroll
        for (int r = 0; r < 4; ++r) oacc[tp][r] *= alpha_r[r];
        bf16x8 b0 = *(const bf16x8*)&RV[tp * 16 + l16][quad * 8];
        bf16x8 b1 = *(const bf16x8*)&RV[tp * 16 + l16][32 + quad * 8];
        oacc[tp] = __builtin_amdgcn_mfma_f32_16x16x32_bf16(pa0, b0, oacc[tp], 0, 0, 0);
        oacc[tp] = __builtin_amdgcn_mfma_f32_16x16x32_bf16(pa1, b1, oacc[tp], 0, 0, 0);
      }
    }
  }

  // epilogue
#pragma unroll
  for (int r = 0; r < 4; ++r) l_i[r] = 1.f / l_i[r];
#pragma unroll
  for (int tp = 0; tp < 4; ++tp) {
    int pcol = tp * 16 + l16;
#pragma unroll
    for (int r = 0; r < 4; ++r) {
      int sg = s0 + sl_base + r;
      O[((size_t)(b * SEQ + sg)) * DM + h * PD + pcol] = f2bf(oacc[tp][r] * l_i[r]);
    }
  }
}

extern "C" void kernel_launch(void* const* d_in, const int* in_sizes, int n_in,
                              void* d_out, int out_size, void* d_ws, size_t ws_size,
                              hipStream_t stream) {
  (void)in_sizes; (void)n_in; (void)out_size; (void)ws_size;
  const void* x  = d_in[0];
  const void* Wq = d_in[1];
  const void* bq = d_in[2];
  const void* Wk = d_in[3];
  const void* bk = d_in[4];
  const void* Wv = d_in[5];
  const void* bv = d_in[6];
  const void* Wp = d_in[7];
  const void* bp = d_in[8];
  const void* Wo = d_in[9];
  const void* bo = d_in[10];
  const void* u  = d_in[11];
  const void* v  = d_in[12];

  char* base = (char*)d_ws;
  int* flag = (int*)base;
  float* pf = (float*)(base + 64);                       // 7168 floats
  u16* wbase = (u16*)(base + 64 + 7168 * 4);
  u16* WT   = wbase;                                     // 5M elems
  u16* xb   = WT + (size_t)5 * DM * DM;                  // 4M (aliased: Vtb)
  u16* sinb = xb + (size_t)2 * SEQ * DM;                 // 2M
  u16* Qb   = sinb + (size_t)SEQ * DM;                   // 4M
  u16* Kb   = Qb + (size_t)2 * SEQ * DM;                 // 4M
  u16* Vb   = Kb + (size_t)2 * SEQ * DM;                 // 4M (aliased: attn out)
  u16* Rb   = Vb + (size_t)2 * SEQ * DM;                 // 2M
  u16* Vtb  = xb;   // x consumed by QKV gemm before transpose_v writes here
  u16* Ab   = Vb;   // V consumed by transpose_v before attention writes here

  detect_kernel<<<1, 256, 0, stream>>>((const u16*)Wq, flag);

  convert_x_kernel<<<(2 * SEQ * DM) / 1024, 256, 0, stream>>>(x, xb, flag);
  ParamPtrs pp;
  pp.p[0] = bq; pp.p[1] = bk; pp.p[2] = bv; pp.p[3] = bp; pp.p[4] = bo;
  pp.p[5] = u;  pp.p[6] = v;
  convert_params_kernel<<<28, 256, 0, stream>>>(pp, pf, flag);

  sinusoid_kernel<<<(SEQ * DM) / 256, 256, 0, stream>>>(sinb);
  transpose5_kernel<<<dim3(16, 16, 5), 256, 0, stream>>>(Wq, Wk, Wv, Wp, Wo, WT, flag);

  GemmArgs qkv;
  qkv.A = xb;
  qkv.Bt0 = WT; qkv.Bt1 = WT + (size_t)DM * DM; qkv.Bt2 = WT + (size_t)2 * DM * DM;
  qkv.b0 = pf; qkv.b1 = pf + 1024; qkv.b2 = pf + 2048;
  qkv.C0 = Qb; qkv.C1 = Kb; qkv.C2 = Vb;
  qkv.N = DM; qkv.K = DM; qkv.flag = flag; qkv.outFp32 = 0;
  gemm_bt_kernel<<<dim3(8, 32, 3), 256, 0, stream>>>(qkv);

  GemmArgs pr;
  pr.A = sinb;
  pr.Bt0 = WT + (size_t)3 * DM * DM; pr.Bt1 = pr.Bt0; pr.Bt2 = pr.Bt0;
  pr.b0 = pf + 3072; pr.b1 = pr.b0; pr.b2 = pr.b0;
  pr.C0 = Rb; pr.C1 = Rb; pr.C2 = Rb;
  pr.N = DM; pr.K = DM; pr.flag = flag; pr.outFp32 = 0;
  gemm_bt_kernel<<<dim3(8, 16, 1), 256, 0, stream>>>(pr);

  transpose_v_kernel<<<dim3(32, 32), 256, 0, stream>>>(Vb, Vtb);
  attn_kernel<<<dim3(32, 32), 256, 0, stream>>>(Qb, Kb, Vtb, Rb, pf, Ab);

  GemmArgs fo;
  fo.A = Ab;
  fo.Bt0 = WT + (size_t)4 * DM * DM; fo.Bt1 = fo.Bt0; fo.Bt2 = fo.Bt0;
  fo.b0 = pf + 4096; fo.b1 = fo.b0; fo.b2 = fo.b0;
  fo.C0 = d_out; fo.C1 = d_out; fo.C2 = d_out;
  fo.N = DM; fo.K = DM; fo.flag = flag; fo.outFp32 = 1;
  gemm_bt_kernel<<<dim3(8, 32, 1), 256, 0, stream>>>(fo);
}

// Round 4
// 406.319 us; speedup vs baseline: 1.6904x; 1.3823x over previous
//
#include <hip/hip_runtime.h>
#include <hip/hip_bf16.h>

typedef unsigned short u16;
typedef unsigned int u32;
typedef __bf16 bf16x8 __attribute__((ext_vector_type(8)));
typedef float f32x4 __attribute__((ext_vector_type(4)));

#define SEQ 2048
#define NH 16
#define PD 64
#define DM 1024

__device__ __forceinline__ float bf2f(u16 s) {
  u32 t = ((u32)s) << 16;
  float f;
  __builtin_memcpy(&f, &t, 4);
  return f;
}
__device__ __forceinline__ u16 f2bf(float f) {
  u32 x;
  __builtin_memcpy(&x, &f, 4);
  x = (x + 0x7fffu + ((x >> 16) & 1u)) >> 16;
  return (u16)x;
}
__device__ __forceinline__ float u2f(u32 b) {
  float f;
  __builtin_memcpy(&f, &b, 4);
  return f;
}
// packed f32x2 -> bf16x2 (RNE), low half = first arg
__device__ __forceinline__ u32 pack2(float a, float b) {
  __hip_bfloat162 h = __float22bfloat162_rn(float2{a, b});
  u32 r;
  __builtin_memcpy(&r, &h, 4);
  return r;
}
// DPP row-rotate (within 16-lane rows) for cross-lane reduction without LDS pipe
template <int C>
__device__ __forceinline__ float dppf(float x) {
  int xi;
  __builtin_memcpy(&xi, &x, 4);
  int yi = __builtin_amdgcn_mov_dpp(xi, C, 0xF, 0xF, false);
  float y;
  __builtin_memcpy(&y, &yi, 4);
  return y;
}
__device__ __forceinline__ float rmax16(float x) {
  x = fmaxf(x, dppf<0x121>(x));
  x = fmaxf(x, dppf<0x122>(x));
  x = fmaxf(x, dppf<0x124>(x));
  x = fmaxf(x, dppf<0x128>(x));
  return x;
}
__device__ __forceinline__ float rsum16(float x) {
  x += dppf<0x121>(x);
  x += dppf<0x122>(x);
  x += dppf<0x124>(x);
  x += dppf<0x128>(x);
  return x;
}

// ---------------- dtype detection (fp32 vs bf16 input buffers) ----------------
__global__ __launch_bounds__(256) void detect_kernel(const u16* __restrict__ probe,
                                                     int* __restrict__ flag) {
  __shared__ int sz[256], sh[256];
  int tid = threadIdx.x;
  int zeros = 0, huge = 0;
  for (int j = 0; j < 16; ++j) {
    int i = tid * 16 + j;
    u16 v = probe[i];
    int e = (v >> 7) & 0xFF;
    if (((i & 1) == 0) && v == 0) zeros++;
    if (e >= 0x8C) huge++;
  }
  sz[tid] = zeros; sh[tid] = huge;
  __syncthreads();
  for (int s = 128; s > 0; s >>= 1) {
    if (tid < s) { sz[tid] += sz[tid + s]; sh[tid] += sh[tid + s]; }
    __syncthreads();
  }
  if (tid == 0) *flag = (sz[0] > 1024 || sh[0] > 200) ? 1 : 0;
}

// ---------------- convert x (4M elems) to bf16 ----------------
__global__ __launch_bounds__(256) void convert_x_kernel(const void* __restrict__ src,
                                                        u16* __restrict__ dst,
                                                        const int* __restrict__ flag) {
  int i = (blockIdx.x * 256 + threadIdx.x) * 4;
  if (*flag) {
    float4 f = *(const float4*)((const float*)src + i);
    u16 o[4] = {f2bf(f.x), f2bf(f.y), f2bf(f.z), f2bf(f.w)};
    *(uint2*)(dst + i) = *(const uint2*)o;
  } else {
    *(uint2*)(dst + i) = *(const uint2*)((const u16*)src + i);
  }
}

// ---------------- convert biases + u + v to fp32 params ----------------
struct ParamPtrs { const void* p[7]; };
__global__ __launch_bounds__(256) void convert_params_kernel(ParamPtrs pp,
                                                             float* __restrict__ pf,
                                                             const int* __restrict__ flag) {
  int idx = blockIdx.x * 256 + threadIdx.x;  // 7168 total
  int seg = idx >> 10, off = idx & 1023;
  const void* s = pp.p[seg];
  pf[idx] = (*flag) ? ((const float*)s)[off] : bf2f(((const u16*)s)[off]);
}

// ---------------- sinusoid position embedding [SEQ, DM] (bf16) ----------------
__global__ __launch_bounds__(256) void sinusoid_kernel(u16* __restrict__ out) {
  int idx = blockIdx.x * 256 + threadIdx.x;
  int s = idx >> 10;
  int i = idx & 1023;
  int j = i & 511;
  float invf = __expf(-(float)j * (9.210340371976184f / 512.0f));
  float ang = (float)s * invf;
  float val = (i < 512) ? sinf(ang) : cosf(ang);
  out[idx] = f2bf(val);
}

// ---------------- transpose + convert the five 1024x1024 weights ----------------
__global__ __launch_bounds__(256) void transpose5_kernel(
    const void* __restrict__ w0, const void* __restrict__ w1,
    const void* __restrict__ w2, const void* __restrict__ w3,
    const void* __restrict__ w4, u16* __restrict__ dst,
    const int* __restrict__ flag) {
  __shared__ u16 t[64][72];
  int z = blockIdx.z;
  const void* src = (z == 0) ? w0 : (z == 1) ? w1 : (z == 2) ? w2 : (z == 3) ? w3 : w4;
  u16* out = dst + (size_t)z * DM * DM;
  int r0 = blockIdx.y * 64, c0 = blockIdx.x * 64;
  int tr = threadIdx.x >> 2;
  int tc = (threadIdx.x & 3) * 16;
  if (*flag) {
    const float* g = (const float*)src + (size_t)(r0 + tr) * DM + c0 + tc;
#pragma unroll
    for (int q = 0; q < 4; ++q) {
      float4 f = *(const float4*)(g + q * 4);
      t[tr][tc + q * 4 + 0] = f2bf(f.x);
      t[tr][tc + q * 4 + 1] = f2bf(f.y);
      t[tr][tc + q * 4 + 2] = f2bf(f.z);
      t[tr][tc + q * 4 + 3] = f2bf(f.w);
    }
  } else {
    const uint4* g = (const uint4*)((const u16*)src + (size_t)(r0 + tr) * DM + c0 + tc);
    uint4 a = g[0], bb = g[1];
    *(uint4*)&t[tr][tc] = a;
    *(uint4*)&t[tr][tc + 8] = bb;
  }
  __syncthreads();
  u16 tmp[16] __attribute__((aligned(16)));
#pragma unroll
  for (int jj = 0; jj < 16; ++jj) tmp[jj] = t[tc + jj][tr];
  uint4* o = (uint4*)(out + (size_t)(c0 + tr) * DM + r0 + tc);
  o[0] = *(const uint4*)&tmp[0];
  o[1] = *(const uint4*)&tmp[8];
}

// ---------------- transpose V [B,S,H,P] -> Vt [B,H,P,S] ----------------
__global__ __launch_bounds__(256) void transpose_v_kernel(
    const u16* __restrict__ V, u16* __restrict__ Vt) {
  __shared__ u16 t[64][72];
  int s0 = blockIdx.x * 64;
  int bh = blockIdx.y;
  int b = bh >> 4, h = bh & 15;
  int tr = threadIdx.x >> 2;
  int tc = (threadIdx.x & 3) * 16;
  const uint4* g = (const uint4*)(V + ((size_t)(b * SEQ + s0 + tr) * NH + h) * PD + tc);
  uint4 a = g[0], bb = g[1];
  *(uint4*)&t[tr][tc] = a;
  *(uint4*)&t[tr][tc + 8] = bb;
  __syncthreads();
  u16 tmp[16] __attribute__((aligned(16)));
#pragma unroll
  for (int jj = 0; jj < 16; ++jj) tmp[jj] = t[tc + jj][tr];
  uint4* o = (uint4*)(Vt + ((size_t)(b * NH + h) * PD + tr) * SEQ + s0 + tc);
  o[0] = *(const uint4*)&tmp[0];
  o[1] = *(const uint4*)&tmp[8];
}

// ---------------- bf16 GEMM, 128x128x32 tiles ----------------
struct GemmArgs {
  const u16* A;
  const u16* Bt0; const u16* Bt1; const u16* Bt2;
  const float* b0; const float* b1; const float* b2;
  void* C0; void* C1; void* C2;
  int N, K;
  const int* flag; int outFp32;
};

__global__ __launch_bounds__(256) void gemm_bt_kernel(GemmArgs p) {
  __shared__ u16 As[128 * 40];
  __shared__ u16 Bs[128 * 40];
  int z = blockIdx.z;
  const u16* A = p.A;
  const u16* Bt = (z == 0) ? p.Bt0 : (z == 1) ? p.Bt1 : p.Bt2;
  const float* bias = (z == 0) ? p.b0 : (z == 1) ? p.b1 : p.b2;
  void* Cv = (z == 0) ? p.C0 : (z == 1) ? p.C1 : p.C2;
  int K = p.K, N = p.N;
  bool f32o = p.outFp32 && (*p.flag);

  int tid = threadIdx.x;
  int wave = tid >> 6, lane = tid & 63;
  int quad = lane >> 4, l16 = lane & 15;
  int m0 = blockIdx.y * 128, n0 = blockIdx.x * 128;
  int wm = (wave >> 1) * 64, wn = (wave & 1) * 64;
  int srow = tid >> 1, scol = (tid & 1) * 16;

  f32x4 acc[4][4] = {};

  const u16* ga = A + (size_t)(m0 + srow) * K + scol;
  const u16* gb = Bt + (size_t)(n0 + srow) * K + scol;

  for (int k0 = 0; k0 < K; k0 += 32) {
    uint4 a0 = *(const uint4*)(ga + k0);
    uint4 a1 = *(const uint4*)(ga + k0 + 8);
    uint4 b0 = *(const uint4*)(gb + k0);
    uint4 b1 = *(const uint4*)(gb + k0 + 8);
    __syncthreads();
    *(uint4*)&As[srow * 40 + scol] = a0;
    *(uint4*)&As[srow * 40 + scol + 8] = a1;
    *(uint4*)&Bs[srow * 40 + scol] = b0;
    *(uint4*)&Bs[srow * 40 + scol + 8] = b1;
    __syncthreads();
    bf16x8 af[4], bfv[4];
#pragma unroll
    for (int i = 0; i < 4; ++i) {
      af[i] = *(const bf16x8*)&As[(wm + i * 16 + l16) * 40 + quad * 8];
      bfv[i] = *(const bf16x8*)&Bs[(wn + i * 16 + l16) * 40 + quad * 8];
    }
#pragma unroll
    for (int tm = 0; tm < 4; ++tm)
#pragma unroll
      for (int tn = 0; tn < 4; ++tn)
        acc[tm][tn] = __builtin_amdgcn_mfma_f32_16x16x32_bf16(af[tm], bfv[tn], acc[tm][tn], 0, 0, 0);
  }

#pragma unroll
  for (int tm = 0; tm < 4; ++tm) {
    int row = m0 + wm + tm * 16 + quad * 4;
#pragma unroll
    for (int tn = 0; tn < 4; ++tn) {
      int col = n0 + wn + tn * 16 + l16;
      float bv = bias[col];
#pragma unroll
      for (int r = 0; r < 4; ++r) {
        float val = acc[tm][tn][r] + bv;
        if (f32o) ((float*)Cv)[(size_t)(row + r) * N + col] = val;
        else ((u16*)Cv)[(size_t)(row + r) * N + col] = f2bf(val);
      }
    }
  }
}

// ---------------- fused rel-attention v2 ----------------
// Q fragments in registers; band validity = uniform threshold on band row,
// applied at store time (zeros), gather-add unconditional. DPP softmax.
__global__ __launch_bounds__(256, 4) void attn_kernel(
    const u16* __restrict__ Q, const u16* __restrict__ Kg,
    const u16* __restrict__ Vtg, const u16* __restrict__ Rg,
    const float* __restrict__ pf,
    u16* __restrict__ O) {
  __shared__ __align__(16) u16 KsP[64][72];  // K tile [t][p] / P probs [s][t]
  __shared__ __align__(16) u16 RV[64][72];   // R band tile [t][p] / V^T tile [p][t]
  __shared__ __align__(16) u16 BbT[128][70]; // pos band transposed [tband][s_local]

  int tid = threadIdx.x, wave = tid >> 6, lane = tid & 63;
  int quad = lane >> 4, l16 = lane & 15;
  int s0 = blockIdx.x * 64;
  int bh = blockIdx.y, b = bh >> 4, h = bh & 15;
  const float* pu = pf + 5 * 1024 + h * PD;
  const float* pv = pf + 6 * 1024 + h * PD;

  int arow = wave * 16 + l16;          // A-frag row (this lane's q row)
  int sl_base = wave * 16 + quad * 4;  // C-layout row base

  // ---- prologue: build Q fragments in registers ----
  bf16x8 qu0, qu1, qv0a, qv1a, qv0b, qv1b;
  {
    const u16* qp = Q + ((size_t)(b * SEQ + s0 + arow)) * DM + h * PD;
    int row2 = s0 + arow + 1;
    if (row2 > SEQ - 1) row2 = SEQ - 1;  // clamped row only feeds masked-out elements
    const u16* qp2 = Q + ((size_t)(b * SEQ + row2)) * DM + h * PD;
    u16 qa[16] __attribute__((aligned(16)));
    u16 qb[16] __attribute__((aligned(16)));
    *(uint4*)&qa[0] = *(const uint4*)(qp + quad * 8);
    *(uint4*)&qa[8] = *(const uint4*)(qp + 32 + quad * 8);
    *(uint4*)&qb[0] = *(const uint4*)(qp2 + quad * 8);
    *(uint4*)&qb[8] = *(const uint4*)(qp2 + 32 + quad * 8);
    u16 fu[16] __attribute__((aligned(16)));
    u16 fv0[16] __attribute__((aligned(16)));
    u16 fv1[16] __attribute__((aligned(16)));
#pragma unroll
    for (int j = 0; j < 8; ++j) {
      float u0 = pu[quad * 8 + j], u1 = pu[32 + quad * 8 + j];
      float v0 = pv[quad * 8 + j], v1 = pv[32 + quad * 8 + j];
      fu[j] = f2bf(bf2f(qa[j]) + u0);
      fu[8 + j] = f2bf(bf2f(qa[8 + j]) + u1);
      fv0[j] = f2bf(bf2f(qa[j]) + v0);
      fv0[8 + j] = f2bf(bf2f(qa[8 + j]) + v1);
      fv1[j] = f2bf(bf2f(qb[j]) + v0);
      fv1[8 + j] = f2bf(bf2f(qb[8 + j]) + v1);
    }
    __builtin_memcpy(&qu0, &fu[0], 16);
    __builtin_memcpy(&qu1, &fu[8], 16);
    __builtin_memcpy(&qv0a, &fv0[0], 16);
    __builtin_memcpy(&qv1a, &fv0[8], 16);
    __builtin_memcpy(&qv0b, &fv1[0], 16);
    __builtin_memcpy(&qv1b, &fv1[8], 16);
  }

  float m_i[4], l_i[4];
#pragma unroll
  for (int r = 0; r < 4; ++r) { m_i[r] = -1e30f; l_i[r] = 0.f; }
  f32x4 oacc[4] = {};

  for (int j0 = 0; j0 < SEQ; j0 += 64) {
    __syncthreads();  // prev PV reads of KsP(P)/RV(V) done; prev gather done
    {
      int tl = tid >> 2, pc = (tid & 3) * 16;
      const uint4* ksrc = (const uint4*)(Kg + ((size_t)(b * SEQ + j0 + tl)) * DM + h * PD + pc);
      uint4 k0 = ksrc[0], k1 = ksrc[1];
      *(uint4*)&KsP[tl][pc] = k0;
      *(uint4*)&KsP[tl][pc + 8] = k1;
    }
    __syncthreads();

    // content scores -> C-layout registers
    f32x4 acc[4];
#pragma unroll
    for (int tn = 0; tn < 4; ++tn) {
      f32x4 a = {};
      bf16x8 b0 = *(const bf16x8*)&KsP[tn * 16 + l16][quad * 8];
      bf16x8 b1 = *(const bf16x8*)&KsP[tn * 16 + l16][32 + quad * 8];
      a = __builtin_amdgcn_mfma_f32_16x16x32_bf16(qu0, b0, a, 0, 0, 0);
      a = __builtin_amdgcn_mfma_f32_16x16x32_bf16(qu1, b1, a, 0, 0, 0);
      acc[tn] = a;
    }

    // positional passes (>=1 pass active per iter)
#pragma unroll 1
    for (int p = 0; p < 2; ++p) {
      int bstart = ((p == 0) ? (SEQ - 65) : -65) + j0 - s0;
      bool act0 = (bstart < SEQ) && (bstart + 64 > 0);
      bool act1 = (bstart + 64 < SEQ) && (bstart + 128 > 0);
      if (!act0 && !act1) continue;
      int thresh = ((p == 0) ? 64 : 65) + s0 - j0;
      bf16x8 pa0 = (p == 0) ? qv0a : qv0b;
      bf16x8 pa1 = (p == 0) ? qv1a : qv1b;
#pragma unroll 1
      for (int hf = 0; hf < 2; ++hf) {
        bool act = hf ? act1 : act0;
        int tb0 = bstart + hf * 64;
        __syncthreads();  // prior gather/band reads + RV frag reads done
        if (act) {
          {
            int rn = tid >> 2, pc = (tid & 3) * 16;
            int tg = tb0 + rn;
            uint4 r0v = make_uint4(0, 0, 0, 0), r1v = r0v;
            if (tg >= 0 && tg < SEQ) {
              const uint4* rsrc = (const uint4*)(Rg + (size_t)tg * DM + h * PD + pc);
              r0v = rsrc[0];
              r1v = rsrc[1];
            }
            *(uint4*)&RV[rn][pc] = r0v;
            *(uint4*)&RV[rn][pc + 8] = r1v;
          }
          __syncthreads();
#pragma unroll
          for (int tt = 0; tt < 4; ++tt) {
            f32x4 pacc = {};
            bf16x8 b0 = *(const bf16x8*)&RV[tt * 16 + l16][quad * 8];
            bf16x8 b1 = *(const bf16x8*)&RV[tt * 16 + l16][32 + quad * 8];
            pacc = __builtin_amdgcn_mfma_f32_16x16x32_bf16(pa0, b0, pacc, 0, 0, 0);
            pacc = __builtin_amdgcn_mfma_f32_16x16x32_bf16(pa1, b1, pacc, 0, 0, 0);
            int tband = hf * 64 + tt * 16 + l16;
            bool val = (p == 0) ? (tband <= thresh) : (tband >= thresh);
            u32 w0 = val ? pack2(pacc[0], pacc[1]) : 0u;
            u32 w1 = val ? pack2(pacc[2], pacc[3]) : 0u;
            *(u32*)&BbT[tband][sl_base] = w0;
            *(u32*)&BbT[tband][sl_base + 2] = w1;
          }
        } else {
#pragma unroll
          for (int tt = 0; tt < 4; ++tt) {
            int tband = hf * 64 + tt * 16 + l16;
            *(u32*)&BbT[tband][sl_base] = 0u;
            *(u32*)&BbT[tband][sl_base + 2] = 0u;
          }
        }
      }
      __syncthreads();  // band stores visible
      // unconditional gather-add (invalid/inactive positions hold 0)
      int base_t = (p == 0) ? 64 : 63;
      const u16* bb = &BbT[0][0];
#pragma unroll
      for (int tn = 0; tn < 4; ++tn) {
        int cl = tn * 16 + l16;
        const u16* pb = bb + (base_t - sl_base - 3 + cl) * 70 + sl_base + 3;
        acc[tn][3] += bf2f(pb[0]);
        acc[tn][2] += bf2f(pb[69]);
        acc[tn][1] += bf2f(pb[138]);
        acc[tn][0] += bf2f(pb[207]);
      }
    }

    // softmax in C-layout registers (DPP reductions over the 16-lane row)
    float alpha_r[4];
#pragma unroll
    for (int r = 0; r < 4; ++r) {
      float v0 = acc[0][r] * 0.125f, v1 = acc[1][r] * 0.125f;
      float v2 = acc[2][r] * 0.125f, v3 = acc[3][r] * 0.125f;
      float mx = fmaxf(fmaxf(v0, v1), fmaxf(v2, v3));
      mx = rmax16(mx);
      float m_new = fmaxf(m_i[r], mx);
      float al = __expf(m_i[r] - m_new);
      u32 w0 = pack2(__expf(v0 - m_new), __expf(v1 - m_new));
      u32 w1 = pack2(__expf(v2 - m_new), __expf(v3 - m_new));
      int row = sl_base + r;
      KsP[row][l16] = (u16)w0;
      KsP[row][16 + l16] = (u16)(w0 >> 16);
      KsP[row][32 + l16] = (u16)w1;
      KsP[row][48 + l16] = (u16)(w1 >> 16);
      float ssum = u2f(w0 << 16) + u2f(w0 & 0xffff0000u) + u2f(w1 << 16) + u2f(w1 & 0xffff0000u);
      ssum = rsum16(ssum);
      l_i[r] = l_i[r] * al + ssum;
      m_i[r] = m_new;
      alpha_r[r] = al;
    }

    // stage V^T
    {
      int tl = tid >> 2, pc = (tid & 3) * 16;
      const uint4* vsrc = (const uint4*)(Vtg + ((size_t)(b * NH + h) * PD + tl) * SEQ + j0 + pc);
      uint4 v0 = vsrc[0], v1 = vsrc[1];
      *(uint4*)&RV[tl][pc] = v0;
      *(uint4*)&RV[tl][pc + 8] = v1;
    }
    __syncthreads();  // P + V visible

    // PV
    {
      bf16x8 pa0 = *(const bf16x8*)&KsP[arow][quad * 8];
      bf16x8 pa1 = *(const bf16x8*)&KsP[arow][32 + quad * 8];
#pragma unroll
      for (int tp = 0; tp < 4; ++tp) {
#pragma unroll
        for (int r = 0; r < 4; ++r) oacc[tp][r] *= alpha_r[r];
        bf16x8 b0 = *(const bf16x8*)&RV[tp * 16 + l16][quad * 8];
        bf16x8 b1 = *(const bf16x8*)&RV[tp * 16 + l16][32 + quad * 8];
        oacc[tp] = __builtin_amdgcn_mfma_f32_16x16x32_bf16(pa0, b0, oacc[tp], 0, 0, 0);
        oacc[tp] = __builtin_amdgcn_mfma_f32_16x16x32_bf16(pa1, b1, oacc[tp], 0, 0, 0);
      }
    }
  }

  // epilogue
#pragma unroll
  for (int r = 0; r < 4; ++r) l_i[r] = 1.f / l_i[r];
#pragma unroll
  for (int tp = 0; tp < 4; ++tp) {
    int pcol = tp * 16 + l16;
#pragma unroll
    for (int r = 0; r < 4; ++r) {
      int sg = s0 + sl_base + r;
      O[((size_t)(b * SEQ + sg)) * DM + h * PD + pcol] = f2bf(oacc[tp][r] * l_i[r]);
    }
  }
}

extern "C" void kernel_launch(void* const* d_in, const int* in_sizes, int n_in,
                              void* d_out, int out_size, void* d_ws, size_t ws_size,
                              hipStream_t stream) {
  (void)in_sizes; (void)n_in; (void)out_size; (void)ws_size;
  const void* x  = d_in[0];
  const void* Wq = d_in[1];
  const void* bq = d_in[2];
  const void* Wk = d_in[3];
  const void* bk = d_in[4];
  const void* Wv = d_in[5];
  const void* bv = d_in[6];
  const void* Wp = d_in[7];
  const void* bp = d_in[8];
  const void* Wo = d_in[9];
  const void* bo = d_in[10];
  const void* u  = d_in[11];
  const void* v  = d_in[12];

  char* base = (char*)d_ws;
  int* flag = (int*)base;
  float* pf = (float*)(base + 64);                       // 7168 floats
  u16* wbase = (u16*)(base + 64 + 7168 * 4);
  u16* WT   = wbase;                                     // 5M elems
  u16* xb   = WT + (size_t)5 * DM * DM;                  // 4M (aliased: Vtb)
  u16* sinb = xb + (size_t)2 * SEQ * DM;                 // 2M
  u16* Qb   = sinb + (size_t)SEQ * DM;                   // 4M
  u16* Kb   = Qb + (size_t)2 * SEQ * DM;                 // 4M
  u16* Vb   = Kb + (size_t)2 * SEQ * DM;                 // 4M (aliased: attn out)
  u16* Rb   = Vb + (size_t)2 * SEQ * DM;                 // 2M
  u16* Vtb  = xb;   // x consumed by QKV gemm before transpose_v writes here
  u16* Ab   = Vb;   // V consumed by transpose_v before attention writes here

  detect_kernel<<<1, 256, 0, stream>>>((const u16*)Wq, flag);

  convert_x_kernel<<<(2 * SEQ * DM) / 1024, 256, 0, stream>>>(x, xb, flag);
  ParamPtrs pp;
  pp.p[0] = bq; pp.p[1] = bk; pp.p[2] = bv; pp.p[3] = bp; pp.p[4] = bo;
  pp.p[5] = u;  pp.p[6] = v;
  convert_params_kernel<<<28, 256, 0, stream>>>(pp, pf, flag);

  sinusoid_kernel<<<(SEQ * DM) / 256, 256, 0, stream>>>(sinb);
  transpose5_kernel<<<dim3(16, 16, 5), 256, 0, stream>>>(Wq, Wk, Wv, Wp, Wo, WT, flag);

  GemmArgs qkv;
  qkv.A = xb;
  qkv.Bt0 = WT; qkv.Bt1 = WT + (size_t)DM * DM; qkv.Bt2 = WT + (size_t)2 * DM * DM;
  qkv.b0 = pf; qkv.b1 = pf + 1024; qkv.b2 = pf + 2048;
  qkv.C0 = Qb; qkv.C1 = Kb; qkv.C2 = Vb;
  qkv.N = DM; qkv.K = DM; qkv.flag = flag; qkv.outFp32 = 0;
  gemm_bt_kernel<<<dim3(8, 32, 3), 256, 0, stream>>>(qkv);

  GemmArgs pr;
  pr.A = sinb;
  pr.Bt0 = WT + (size_t)3 * DM * DM; pr.Bt1 = pr.Bt0; pr.Bt2 = pr.Bt0;
  pr.b0 = pf + 3072; pr.b1 = pr.b0; pr.b2 = pr.b0;
  pr.C0 = Rb; pr.C1 = Rb; pr.C2 = Rb;
  pr.N = DM; pr.K = DM; pr.flag = flag; pr.outFp32 = 0;
  gemm_bt_kernel<<<dim3(8, 16, 1), 256, 0, stream>>>(pr);

  transpose_v_kernel<<<dim3(32, 32), 256, 0, stream>>>(Vb, Vtb);
  attn_kernel<<<dim3(32, 32), 256, 0, stream>>>(Qb, Kb, Vtb, Rb, pf, Ab);

  GemmArgs fo;
  fo.A = Ab;
  fo.Bt0 = WT + (size_t)4 * DM * DM; fo.Bt1 = fo.Bt0; fo.Bt2 = fo.Bt0;
  fo.b0 = pf + 4096; fo.b1 = fo.b0; fo.b2 = fo.b0;
  fo.C0 = d_out; fo.C1 = d_out; fo.C2 = d_out;
  fo.N = DM; fo.K = DM; fo.flag = flag; fo.outFp32 = 1;
  gemm_bt_kernel<<<dim3(8, 32, 1), 256, 0, stream>>>(fo);
}